// Round 12
// baseline (682.130 us; speedup 1.0000x reference)
//
#include <hip/hip_runtime.h>
#include <cfloat>

#define NB 4
#define NN 4096
#define NS 1024
#define NC1 128
#define NC2 256
#define NCO 128
#define NCC 384
#define NK 16
#define KCHUNK 1024
#define KCAP 128
#define KPAD 129

// NOTE on numerics: the reference computes squared distances in the EXPANDED
// form ||a||^2 + ||b||^2 - 2 a.b (see _sqdist). Top-k selections sit on
// near-ties whose resolution depends on the exact fp bits, so both selection
// kernels below replicate numpy's op order exactly with non-contractible
// __fmul_rn/__fadd_rn/__fsub_rn (no FMA fusion allowed).

__device__ __forceinline__ float norm3_np(float x, float y, float z) {
  return __fadd_rn(__fadd_rn(__fmul_rn(x, x), __fmul_rn(y, y)), __fmul_rn(z, z));
}

__device__ __forceinline__ float sqdist_np(float nq, float ns,
                                           float qx, float qy, float qz,
                                           float sx, float sy, float sz) {
  float dot = __fadd_rn(__fadd_rn(__fmul_rn(qx, sx), __fmul_rn(qy, sy)),
                        __fmul_rn(qz, sz));
  return __fsub_rn(__fadd_rn(nq, ns), __fmul_rn(2.0f, dot));
}

// ---------- generic 32x32 LDS-tiled transpose with strided output ----------
__global__ void transpose_k(const float* __restrict__ in, float* __restrict__ out,
                            int rows_in, int cols_in, long in_bs, long out_bs, int out_rs) {
  __shared__ float tile[32][33];
  const int b = blockIdx.z;
  const int c0 = blockIdx.x * 32, r0 = blockIdx.y * 32;
  const float* ib = in + (long)b * in_bs;
  float* ob = out + (long)b * out_bs;
#pragma unroll
  for (int k = 0; k < 32; k += 8) {
    tile[threadIdx.y + k][threadIdx.x] =
        ib[(long)(r0 + threadIdx.y + k) * cols_in + c0 + threadIdx.x];
  }
  __syncthreads();
#pragma unroll
  for (int k = 0; k < 32; k += 8) {
    ob[(long)(c0 + threadIdx.y + k) * out_rs + (r0 + threadIdx.x)] =
        tile[threadIdx.x][threadIdx.y + k];
  }
}

// ---------- 3-point interpolation: top-3 LARGEST distances (faithful) ----------
// block: 256 threads = 32 queries x 8 lanes; grid (N/32, B)
__global__ __launch_bounds__(256) void interp_top3_k(const float* __restrict__ xyz1,
                                                     const float* __restrict__ xyz2,
                                                     float* __restrict__ wW,
                                                     int* __restrict__ wIdx) {
  __shared__ float sx[NS], sy[NS], sz[NS], sn[NS];
  __shared__ float md[256 * 3];
  __shared__ int mi[256 * 3];
  const int b = blockIdx.y;
  const int tid = threadIdx.x;
  for (int i = tid; i < NS; i += 256) {
    long base = ((long)b * NS + i) * 3;
    float x = xyz2[base], y = xyz2[base + 1], z = xyz2[base + 2];
    sx[i] = x; sy[i] = y; sz[i] = z;
    sn[i] = norm3_np(x, y, z);
  }
  __syncthreads();
  const int q = (blockIdx.x << 5) + (tid >> 3);
  const int lane = tid & 7;
  long qb = ((long)b * NN + q) * 3;
  const float qx = xyz1[qb], qy = xyz1[qb + 1], qz = xyz1[qb + 2];
  const float nq = norm3_np(qx, qy, qz);
  float bd[3] = {-FLT_MAX, -FLT_MAX, -FLT_MAX};
  int bi[3] = {0x7fffffff, 0x7fffffff, 0x7fffffff};
  for (int s = lane; s < NS; s += 8) {
    float d = sqdist_np(nq, sn[s], qx, qy, qz, sx[s], sy[s], sz[s]);
    float cd = d; int ci = s;
#pragma unroll
    for (int j = 0; j < 3; ++j) {
      bool gt = cd > bd[j];                  // strict: tie keeps earlier (lower idx)
      float f = fmaxf(cd, bd[j]);
      float bk = fminf(cd, bd[j]);
      int fi = gt ? ci : bi[j];
      int ki = gt ? bi[j] : ci;
      bd[j] = f; bi[j] = fi; cd = bk; ci = ki;
    }
  }
#pragma unroll
  for (int j = 0; j < 3; ++j) { md[tid * 3 + j] = bd[j]; mi[tid * 3 + j] = bi[j]; }
  __syncthreads();
  if (lane == 0) {
    int p0 = 0, p1 = 0, p2 = 0, p3 = 0, p4 = 0, p5 = 0, p6 = 0, p7 = 0;
    float od[3]; int oi[3];
#pragma unroll
    for (int j = 0; j < 3; ++j) {
      float bv = -FLT_MAX; int bidx = 0x7fffffff; int bl = 0;
#define ITOP_CAND(l, pl)                                                     \
      {                                                                      \
        float t = (pl < 3) ? md[(tid + l) * 3 + pl] : -FLT_MAX;              \
        int ti = (pl < 3) ? mi[(tid + l) * 3 + pl] : 0x7fffffff;             \
        if (t > bv || (t == bv && ti < bidx)) { bv = t; bidx = ti; bl = l; } \
      }
      ITOP_CAND(0, p0) ITOP_CAND(1, p1) ITOP_CAND(2, p2) ITOP_CAND(3, p3)
      ITOP_CAND(4, p4) ITOP_CAND(5, p5) ITOP_CAND(6, p6) ITOP_CAND(7, p7)
#undef ITOP_CAND
      od[j] = bv; oi[j] = bidx;
      p0 += (bl == 0); p1 += (bl == 1); p2 += (bl == 2); p3 += (bl == 3);
      p4 += (bl == 4); p5 += (bl == 5); p6 += (bl == 6); p7 += (bl == 7);
    }
    float r0 = 1.f / (od[0] + 1e-8f);
    float r1 = 1.f / (od[1] + 1e-8f);
    float r2 = 1.f / (od[2] + 1e-8f);
    float sR = __fadd_rn(__fadd_rn(r0, r1), r2);
    long obase = ((long)b * NN + q) * 3;
    wW[obase + 0] = r0 / sR; wW[obase + 1] = r1 / sR; wW[obase + 2] = r2 / sR;
    wIdx[obase + 0] = oi[0]; wIdx[obase + 1] = oi[1]; wIdx[obase + 2] = oi[2];
  }
}

// ---------- fill interp channels of nt (cols 128..383) ----------
__global__ __launch_bounds__(256) void interp_fill_k(const float* __restrict__ p2t,
                                                     const float* __restrict__ wW,
                                                     const int* __restrict__ wIdx,
                                                     float* __restrict__ nt) {
  const int q = (blockIdx.x << 1) + (threadIdx.x >> 7);
  const int co = threadIdx.x & 127;
  const int b = q >> 12;
  long wb = (long)q * 3;
  float w0 = wW[wb], w1 = wW[wb + 1], w2 = wW[wb + 2];
  int i0 = wIdx[wb], i1 = wIdx[wb + 1], i2 = wIdx[wb + 2];
  const float* r0 = p2t + ((long)(b << 10) + i0) * NC2;
  const float* r1 = p2t + ((long)(b << 10) + i1) * NC2;
  const float* r2 = p2t + ((long)(b << 10) + i2) * NC2;
  float* orow = nt + (long)q * NCC + NC1;
#pragma unroll
  for (int h = 0; h < 2; ++h) {
    int c = co + 128 * h;
    orow[c] = w0 * r0[c] + w1 * r1[c] + w2 * r2[c];
  }
}

// ---------- f32 tiled GEMM (R6-proven 64x128 tile, 256 blocks) ----------
template <int C>
__global__ __launch_bounds__(256) void gemm_bias_k(const float* __restrict__ feat,
                                                   const float* __restrict__ W,
                                                   const float* __restrict__ bias,
                                                   float* __restrict__ out) {
  __shared__ float fL[64][36];
  __shared__ float wL[128][36];
  const int r0 = blockIdx.x * 64;
  const int tid = threadIdx.x;
  const int tn = tid & 15;
  const int to = tid >> 4;
  float acc[4][8];
#pragma unroll
  for (int i = 0; i < 4; ++i)
#pragma unroll
    for (int j = 0; j < 8; ++j) acc[i][j] = 0.f;

  for (int c0 = 0; c0 < C; c0 += 32) {
#pragma unroll
    for (int k = 0; k < 8; ++k) {
      int e = tid + 256 * k;
      int rr = e >> 5, cc = e & 31;
      fL[rr][cc] = feat[(long)(r0 + rr) * C + c0 + cc];
    }
#pragma unroll
    for (int k = 0; k < 16; ++k) {
      int e = tid + 256 * k;
      int rr = e >> 5, cc = e & 31;
      wL[rr][cc] = W[(long)rr * C + c0 + cc];
    }
    __syncthreads();
#pragma unroll
    for (int cc4 = 0; cc4 < 32; cc4 += 4) {
      float4 fv[4], wv[8];
#pragma unroll
      for (int i = 0; i < 4; ++i) fv[i] = *(const float4*)&fL[tn + 16 * i][cc4];
#pragma unroll
      for (int j = 0; j < 8; ++j) wv[j] = *(const float4*)&wL[to + 16 * j][cc4];
#pragma unroll
      for (int i = 0; i < 4; ++i)
#pragma unroll
        for (int j = 0; j < 8; ++j) {
          acc[i][j] += fv[i].x * wv[j].x + fv[i].y * wv[j].y +
                       fv[i].z * wv[j].z + fv[i].w * wv[j].w;
        }
    }
    __syncthreads();
  }
  const int b = r0 >> 12;
  const int n0 = r0 & 4095;
#pragma unroll
  for (int i = 0; i < 4; ++i) {
    int n = n0 + tn + 16 * i;
#pragma unroll
    for (int j = 0; j < 8; ++j) {
      int o = to + 16 * j;
      out[((long)(b * NCO + o) << 12) + n] = acc[i][j] + bias[o];
    }
  }
}

// ---------- BN stats per channel over (B, N) ----------
__global__ __launch_bounds__(256) void bn_stats_k(const float* __restrict__ v,
                                                  const float* __restrict__ gamma,
                                                  const float* __restrict__ beta,
                                                  float* __restrict__ stats, int relu_in) {
  __shared__ float rs[256], rq[256];
  const int o = blockIdx.x, tid = threadIdx.x;
  float s = 0.f;
  float vals_mean;
  for (int i = tid; i < NB * NN; i += 256) {
    int b = i >> 12, n = i & 4095;
    float val = v[(((long)b * NCO + o) << 12) + n];
    if (relu_in) val = fmaxf(val, 0.f);
    s += val;
  }
  rs[tid] = s;
  __syncthreads();
  for (int off = 128; off > 0; off >>= 1) {
    if (tid < off) rs[tid] += rs[tid + off];
    __syncthreads();
  }
  vals_mean = rs[0] * (1.f / 16384.f);
  float ss = 0.f;
  for (int i = tid; i < NB * NN; i += 256) {
    int b = i >> 12, n = i & 4095;
    float val = v[(((long)b * NCO + o) << 12) + n];
    if (relu_in) val = fmaxf(val, 0.f);
    float c = val - vals_mean;
    ss += c * c;
  }
  rq[tid] = ss;
  __syncthreads();
  for (int off = 128; off > 0; off >>= 1) {
    if (tid < off) rq[tid] += rq[tid + off];
    __syncthreads();
  }
  if (tid == 0) {
    float var = rq[0] * (1.f / 16384.f);
    float inv = rsqrtf(var + 1e-5f);
    stats[o] = vals_mean;
    stats[128 + o] = inv * gamma[o];
    stats[256 + o] = beta[o];
  }
}

// ---------- apply fuse BN + ReLU; write x [B,CO,N] and xt [B,N,CO] ----------
__global__ void fuse_apply_k(const float* __restrict__ xp, const float* __restrict__ stats,
                             float* __restrict__ x, float* __restrict__ xt) {
  const int stride = gridDim.x * blockDim.x;
  for (int idx = blockIdx.x * blockDim.x + threadIdx.x; idx < NB * NCO * NN; idx += stride) {
    int o = (idx >> 12) & 127;
    int b = idx >> 19;
    int n = idx & 4095;
    float v = (xp[idx] - stats[o]) * stats[128 + o] + stats[256 + o];
    v = fmaxf(v, 0.f);
    x[idx] = v;
    xt[(((long)b << 12) + n) * NCO + o] = v;
  }
}

// ---------- KNN(16): ballot compaction, 16 lanes/query; 16 q x 16 lanes ----------
// Grid (N/16, B) = 1024 blocks -> 4 blocks/CU (LDS 32.9 KB) = 4 waves/SIMD,
// double R11's TLP.
// Pass 1: per-lane top-2 over its 256-cand stream; PAIR-COMBINE via
//   shfl_xor(1) (2nd-smallest of the lane-pair's 512-cand stream -- R6's
//   proven combine) -> tau = max over the query's 8 pairs. Union of per-pair
//   top-2 = 16 candidates -> tau >= exact d16: SAFE, and tau's distribution
//   is identical to R11's (mean survivors ~37; KCAP=128 -> P(overflow)
//   ~1.5e-5/query).
// Pass 2: ballot compaction (R11-proven, 16-bit group mask), register count,
//   no atomics.
// Pass 3 MERGE-FREE: every lane of the query redundantly ladders the full
//   survivor buffer (LDS broadcast reads) with the order-independent
//   lex-(d,idx) insert -> all 16 lanes hold the identical sorted top-16;
//   lane j writes element j. No lane-0 serial merge, no LDS reuse aliasing.
// Overflow fallback (P~0.25 queries/run): redundant tau-guarded scan of all
//   candidates in index order (strict-d ladder, stable) -- correct always.
__global__ __launch_bounds__(256) void knn_k(const float* __restrict__ xyz1,
                                             int* __restrict__ knn) {
  __shared__ float4 sc[KCHUNK];      // 16 KB
  __shared__ float bufd[16][KPAD];   // 8.3 KB
  __shared__ int bufi[16][KPAD];     // 8.3 KB
  const int b = blockIdx.y;
  const int tid = threadIdx.x;
  const int ql = tid >> 4;           // local query 0..15
  const int q = (blockIdx.x << 4) + ql;
  const int lane = tid & 15;
  const int gb = (tid & 63) - lane;  // 16-lane group base within the wave
  const long qb = ((long)b * NN + q) * 3;
  const float qx = xyz1[qb], qy = xyz1[qb + 1], qz = xyz1[qb + 2];
  const float nq = norm3_np(qx, qy, qz);

  // ---- pass 1: per-lane top-2, then pair-combined tau ----
  float t0 = FLT_MAX, t1 = FLT_MAX;
  for (int ch = 0; ch < 4; ++ch) {
    for (int i = tid; i < KCHUNK; i += 256) {
      long base = ((long)b * NN + ch * KCHUNK + i) * 3;
      float x = xyz1[base], y = xyz1[base + 1], z = xyz1[base + 2];
      sc[i] = make_float4(x, y, z, norm3_np(x, y, z));
    }
    __syncthreads();
    for (int i = lane; i < KCHUNK; i += 16) {
      float4 cc = sc[i];
      float d = sqdist_np(nq, cc.w, qx, qy, qz, cc.x, cc.y, cc.z);
      float hi = fmaxf(d, t0);
      t0 = fminf(d, t0);
      t1 = fminf(hi, t1);
    }
    __syncthreads();
  }
  // pair-combine (xor 1): 2nd-smallest of the pair's union (R6 formula)
  float p0 = __shfl_xor(t0, 1, 64);
  float p1 = __shfl_xor(t1, 1, 64);
  float tau = fminf(fmaxf(t0, p0), fminf(t1, p1));
  // max over the query's 8 pairs
  tau = fmaxf(tau, __shfl_xor(tau, 2, 64));
  tau = fmaxf(tau, __shfl_xor(tau, 4, 64));
  tau = fmaxf(tau, __shfl_xor(tau, 8, 64));

  // ---- pass 2: ballot-compacted survivor collection ----
  int mycnt = 0;  // uniform across the query's 16 lanes
  for (int ch = 0; ch < 4; ++ch) {
    for (int i = tid; i < KCHUNK; i += 256) {
      long base = ((long)b * NN + ch * KCHUNK + i) * 3;
      float x = xyz1[base], y = xyz1[base + 1], z = xyz1[base + 2];
      sc[i] = make_float4(x, y, z, norm3_np(x, y, z));
    }
    __syncthreads();
    const int cb = ch * KCHUNK;
    for (int i = lane; i < KCHUNK; i += 16) {
      float4 cc = sc[i];
      float d = sqdist_np(nq, cc.w, qx, qy, qz, cc.x, cc.y, cc.z);
      bool surv = (d <= tau);
      unsigned long long m = __ballot(surv);
      unsigned gm = (unsigned)((m >> gb) & 0xFFFFull);
      if (surv) {
        int pos = mycnt + __popc(gm & ((1u << lane) - 1u));
        if (pos < KCAP) { bufd[ql][pos] = d; bufi[ql][pos] = cb + i; }
      }
      mycnt += __popc(gm);
    }
    __syncthreads();
  }

  // ---- pass 3: redundant exact top-16 (all 16 lanes identical) ----
  float bd[NK]; int bi[NK];
#pragma unroll
  for (int j = 0; j < NK; ++j) { bd[j] = FLT_MAX; bi[j] = 0x7fffffff; }
  if (mycnt > KCAP) {
    // fallback: redundant tau-guarded scan, index order (strict-d -> stable)
    for (int s = 0; s < NN; ++s) {
      long base = ((long)b * NN + s) * 3;
      float x = xyz1[base], y = xyz1[base + 1], z = xyz1[base + 2];
      float d = sqdist_np(nq, norm3_np(x, y, z), qx, qy, qz, x, y, z);
      if (d <= tau) {
        float cd = d; int ci = s;
#pragma unroll
        for (int j = 0; j < NK; ++j) {
          bool lt = cd < bd[j];
          float dmin = fminf(cd, bd[j]);
          float dmax = fmaxf(cd, bd[j]);
          int imin = lt ? ci : bi[j];
          int imax = lt ? bi[j] : ci;
          bd[j] = dmin; bi[j] = imin; cd = dmax; ci = imax;
        }
      }
    }
  } else {
    for (int j0 = 0; j0 < mycnt; ++j0) {
      float cd = bufd[ql][j0]; int ci = bufi[ql][j0];   // broadcast read
#pragma unroll
      for (int j = 0; j < NK; ++j) {
        bool lt = (cd < bd[j]) || (cd == bd[j] && ci < bi[j]);  // lex (d, idx)
        float nd = lt ? cd : bd[j];
        float xd = lt ? bd[j] : cd;
        int ni = lt ? ci : bi[j];
        int xi = lt ? bi[j] : ci;
        bd[j] = nd; bi[j] = ni; cd = xd; ci = xi;
      }
    }
  }
  // lane j writes element j (all lanes hold identical sorted arrays)
  const long obase = ((long)b * NN + q) * NK;
#pragma unroll
  for (int j = 0; j < NK; ++j) {
    if (lane == j) knn[obase + j] = bi[j];
  }
}

// ---------- Laplacian gather: dxt[q][o] = sum_k xt[nbr_k][o] - xt[q][o] ----------
__global__ __launch_bounds__(256) void lap_gather_k(const float* __restrict__ xt,
                                                    const int* __restrict__ knn,
                                                    float* __restrict__ dxt) {
  const int q = (blockIdx.x << 1) + (threadIdx.x >> 7);
  const int o = threadIdx.x & 127;
  const int b = q >> 12;
  const int* kid = knn + (long)q * NK;
  const long bb = ((long)b << 12) * NCO;
  float s = 0.f;
#pragma unroll
  for (int k = 0; k < NK; ++k) {
    int m = kid[k];
    s += xt[bb + (long)m * NCO + o];
  }
  dxt[(long)q * NCO + o] = s - xt[(long)q * NCO + o];
}

// ---------- final: out = x + BN(relu(h_pre)) ----------
__global__ void final_k(const float* __restrict__ x, const float* __restrict__ hp,
                        const float* __restrict__ stats, float* __restrict__ out) {
  const int stride = gridDim.x * blockDim.x;
  for (int idx = blockIdx.x * blockDim.x + threadIdx.x; idx < NB * NCO * NN; idx += stride) {
    int o = (idx >> 12) & 127;
    float r = fmaxf(hp[idx], 0.f);
    out[idx] = x[idx] + (r - stats[o]) * stats[128 + o] + stats[256 + o];
  }
}

extern "C" void kernel_launch(void* const* d_in, const int* in_sizes, int n_in,
                              void* d_out, int out_size, void* d_ws, size_t ws_size,
                              hipStream_t stream) {
  const float* xyz1 = (const float*)d_in[0];
  const float* xyz2 = (const float*)d_in[1];
  const float* points1 = (const float*)d_in[2];
  const float* points2 = (const float*)d_in[3];
  const float* fuse_w = (const float*)d_in[4];
  const float* fuse_b = (const float*)d_in[5];
  const float* fuse_g = (const float*)d_in[6];
  const float* fuse_be = (const float*)d_in[7];
  const float* lu_w = (const float*)d_in[8];
  const float* lu_b = (const float*)d_in[9];
  const float* lu_g = (const float*)d_in[10];
  const float* lu_be = (const float*)d_in[11];
  (void)in_sizes; (void)n_in; (void)out_size; (void)ws_size;

  char* ws = (char*)d_ws;
  float* p2t = (float*)(ws);                   // 4,194,304 B  [B,S,C2]
  float* wW = (float*)(ws + 4194304);          //   196,608 B  [B,N,3]
  int* wIdx = (int*)(ws + 4390912);            //   196,608 B
  float* st1 = (float*)(ws + 4587520);         //     1,536 B
  float* st2 = (float*)(ws + 4589056);         //     1,536 B
  int* knn = (int*)(ws + 4590592);             // 1,048,576 B  [B,N,16]
  float* nt = (float*)(ws + 5639168);          // 25,165,824 B [B*N,384]
  float* xp = (float*)(ws + 30804992);         // 8,388,608 B  [B,CO,N]
  float* x = (float*)(ws + 39193600);          // 8,388,608 B  [B,CO,N]
  // nt is dead after the fuse GEMM -> reuse its 25.1 MB for xt/dxt/hp
  float* xt = nt;                  // [B,N,CO]
  float* dxt = nt + 2097152;       // [B*N,CO]
  float* hp = nt + 4194304;        // [B,CO,N]

  dim3 tb(32, 8);
  transpose_k<<<dim3(32, 8, NB), tb, 0, stream>>>(points2, p2t, 256, 1024, 262144L, 262144L, 256);
  transpose_k<<<dim3(128, 4, NB), tb, 0, stream>>>(points1, nt, 128, 4096, 524288L, 1572864L, 384);
  interp_top3_k<<<dim3(128, NB), 256, 0, stream>>>(xyz1, xyz2, wW, wIdx);
  interp_fill_k<<<8192, 256, 0, stream>>>(p2t, wW, wIdx, nt);
  gemm_bias_k<NCC><<<256, 256, 0, stream>>>(nt, fuse_w, fuse_b, xp);
  bn_stats_k<<<128, 256, 0, stream>>>(xp, fuse_g, fuse_be, st1, 0);
  fuse_apply_k<<<2048, 256, 0, stream>>>(xp, st1, x, xt);
  knn_k<<<dim3(256, NB), 256, 0, stream>>>(xyz1, knn);
  lap_gather_k<<<8192, 256, 0, stream>>>(xt, knn, dxt);
  gemm_bias_k<NCO><<<256, 256, 0, stream>>>(dxt, lu_w, lu_b, hp);
  bn_stats_k<<<128, 256, 0, stream>>>(hp, lu_g, lu_be, st2, 1);
  final_k<<<2048, 256, 0, stream>>>(x, hp, st2, (float*)d_out);
}

// Round 13
// 286.396 us; speedup vs baseline: 2.3818x; 2.3818x over previous
//
#include <hip/hip_runtime.h>
#include <cfloat>

#define NB 4
#define NN 4096
#define NS 1024
#define NC1 128
#define NC2 256
#define NCO 128
#define NCC 384
#define NK 16
#define KCHUNK 2048
#define KCAP 160
#define KPAD 161

// NOTE on numerics: the reference computes squared distances in the EXPANDED
// form ||a||^2 + ||b||^2 - 2 a.b (see _sqdist). Top-k selections sit on
// near-ties whose resolution depends on the exact fp bits, so both selection
// kernels below replicate numpy's op order exactly with non-contractible
// __fmul_rn/__fadd_rn/__fsub_rn (no FMA fusion allowed).

__device__ __forceinline__ float norm3_np(float x, float y, float z) {
  return __fadd_rn(__fadd_rn(__fmul_rn(x, x), __fmul_rn(y, y)), __fmul_rn(z, z));
}

__device__ __forceinline__ float sqdist_np(float nq, float ns,
                                           float qx, float qy, float qz,
                                           float sx, float sy, float sz) {
  float dot = __fadd_rn(__fadd_rn(__fmul_rn(qx, sx), __fmul_rn(qy, sy)),
                        __fmul_rn(qz, sz));
  return __fsub_rn(__fadd_rn(nq, ns), __fmul_rn(2.0f, dot));
}

// ---------- generic 32x32 LDS-tiled transpose with strided output ----------
__global__ void transpose_k(const float* __restrict__ in, float* __restrict__ out,
                            int rows_in, int cols_in, long in_bs, long out_bs, int out_rs) {
  __shared__ float tile[32][33];
  const int b = blockIdx.z;
  const int c0 = blockIdx.x * 32, r0 = blockIdx.y * 32;
  const float* ib = in + (long)b * in_bs;
  float* ob = out + (long)b * out_bs;
#pragma unroll
  for (int k = 0; k < 32; k += 8) {
    tile[threadIdx.y + k][threadIdx.x] =
        ib[(long)(r0 + threadIdx.y + k) * cols_in + c0 + threadIdx.x];
  }
  __syncthreads();
#pragma unroll
  for (int k = 0; k < 32; k += 8) {
    ob[(long)(c0 + threadIdx.y + k) * out_rs + (r0 + threadIdx.x)] =
        tile[threadIdx.x][threadIdx.y + k];
  }
}

// ---------- 3-point interpolation: top-3 LARGEST distances (faithful) ----------
// block: 256 threads = 32 queries x 8 lanes; grid (N/32, B)
__global__ __launch_bounds__(256) void interp_top3_k(const float* __restrict__ xyz1,
                                                     const float* __restrict__ xyz2,
                                                     float* __restrict__ wW,
                                                     int* __restrict__ wIdx) {
  __shared__ float sx[NS], sy[NS], sz[NS], sn[NS];
  __shared__ float md[256 * 3];
  __shared__ int mi[256 * 3];
  const int b = blockIdx.y;
  const int tid = threadIdx.x;
  for (int i = tid; i < NS; i += 256) {
    long base = ((long)b * NS + i) * 3;
    float x = xyz2[base], y = xyz2[base + 1], z = xyz2[base + 2];
    sx[i] = x; sy[i] = y; sz[i] = z;
    sn[i] = norm3_np(x, y, z);
  }
  __syncthreads();
  const int q = (blockIdx.x << 5) + (tid >> 3);
  const int lane = tid & 7;
  long qb = ((long)b * NN + q) * 3;
  const float qx = xyz1[qb], qy = xyz1[qb + 1], qz = xyz1[qb + 2];
  const float nq = norm3_np(qx, qy, qz);
  float bd[3] = {-FLT_MAX, -FLT_MAX, -FLT_MAX};
  int bi[3] = {0x7fffffff, 0x7fffffff, 0x7fffffff};
  for (int s = lane; s < NS; s += 8) {
    float d = sqdist_np(nq, sn[s], qx, qy, qz, sx[s], sy[s], sz[s]);
    float cd = d; int ci = s;
#pragma unroll
    for (int j = 0; j < 3; ++j) {
      bool gt = cd > bd[j];                  // strict: tie keeps earlier (lower idx)
      float f = fmaxf(cd, bd[j]);
      float bk = fminf(cd, bd[j]);
      int fi = gt ? ci : bi[j];
      int ki = gt ? bi[j] : ci;
      bd[j] = f; bi[j] = fi; cd = bk; ci = ki;
    }
  }
#pragma unroll
  for (int j = 0; j < 3; ++j) { md[tid * 3 + j] = bd[j]; mi[tid * 3 + j] = bi[j]; }
  __syncthreads();
  if (lane == 0) {
    int p0 = 0, p1 = 0, p2 = 0, p3 = 0, p4 = 0, p5 = 0, p6 = 0, p7 = 0;
    float od[3]; int oi[3];
#pragma unroll
    for (int j = 0; j < 3; ++j) {
      float bv = -FLT_MAX; int bidx = 0x7fffffff; int bl = 0;
#define ITOP_CAND(l, pl)                                                     \
      {                                                                      \
        float t = (pl < 3) ? md[(tid + l) * 3 + pl] : -FLT_MAX;              \
        int ti = (pl < 3) ? mi[(tid + l) * 3 + pl] : 0x7fffffff;             \
        if (t > bv || (t == bv && ti < bidx)) { bv = t; bidx = ti; bl = l; } \
      }
      ITOP_CAND(0, p0) ITOP_CAND(1, p1) ITOP_CAND(2, p2) ITOP_CAND(3, p3)
      ITOP_CAND(4, p4) ITOP_CAND(5, p5) ITOP_CAND(6, p6) ITOP_CAND(7, p7)
#undef ITOP_CAND
      od[j] = bv; oi[j] = bidx;
      p0 += (bl == 0); p1 += (bl == 1); p2 += (bl == 2); p3 += (bl == 3);
      p4 += (bl == 4); p5 += (bl == 5); p6 += (bl == 6); p7 += (bl == 7);
    }
    float r0 = 1.f / (od[0] + 1e-8f);
    float r1 = 1.f / (od[1] + 1e-8f);
    float r2 = 1.f / (od[2] + 1e-8f);
    float sR = __fadd_rn(__fadd_rn(r0, r1), r2);
    long obase = ((long)b * NN + q) * 3;
    wW[obase + 0] = r0 / sR; wW[obase + 1] = r1 / sR; wW[obase + 2] = r2 / sR;
    wIdx[obase + 0] = oi[0]; wIdx[obase + 1] = oi[1]; wIdx[obase + 2] = oi[2];
  }
}

// ---------- fill interp channels of nt (cols 128..383) ----------
__global__ __launch_bounds__(256) void interp_fill_k(const float* __restrict__ p2t,
                                                     const float* __restrict__ wW,
                                                     const int* __restrict__ wIdx,
                                                     float* __restrict__ nt) {
  const int q = (blockIdx.x << 1) + (threadIdx.x >> 7);
  const int co = threadIdx.x & 127;
  const int b = q >> 12;
  long wb = (long)q * 3;
  float w0 = wW[wb], w1 = wW[wb + 1], w2 = wW[wb + 2];
  int i0 = wIdx[wb], i1 = wIdx[wb + 1], i2 = wIdx[wb + 2];
  const float* r0 = p2t + ((long)(b << 10) + i0) * NC2;
  const float* r1 = p2t + ((long)(b << 10) + i1) * NC2;
  const float* r2 = p2t + ((long)(b << 10) + i2) * NC2;
  float* orow = nt + (long)q * NCC + NC1;
#pragma unroll
  for (int h = 0; h < 2; ++h) {
    int c = co + 128 * h;
    orow[c] = w0 * r0[c] + w1 * r1[c] + w2 * r2[c];
  }
}

// ---------- f32 tiled GEMM (R6-proven 64x128 tile, 256 blocks) ----------
template <int C>
__global__ __launch_bounds__(256) void gemm_bias_k(const float* __restrict__ feat,
                                                   const float* __restrict__ W,
                                                   const float* __restrict__ bias,
                                                   float* __restrict__ out) {
  __shared__ float fL[64][36];
  __shared__ float wL[128][36];
  const int r0 = blockIdx.x * 64;
  const int tid = threadIdx.x;
  const int tn = tid & 15;
  const int to = tid >> 4;
  float acc[4][8];
#pragma unroll
  for (int i = 0; i < 4; ++i)
#pragma unroll
    for (int j = 0; j < 8; ++j) acc[i][j] = 0.f;

  for (int c0 = 0; c0 < C; c0 += 32) {
#pragma unroll
    for (int k = 0; k < 8; ++k) {
      int e = tid + 256 * k;
      int rr = e >> 5, cc = e & 31;
      fL[rr][cc] = feat[(long)(r0 + rr) * C + c0 + cc];
    }
#pragma unroll
    for (int k = 0; k < 16; ++k) {
      int e = tid + 256 * k;
      int rr = e >> 5, cc = e & 31;
      wL[rr][cc] = W[(long)rr * C + c0 + cc];
    }
    __syncthreads();
#pragma unroll
    for (int cc4 = 0; cc4 < 32; cc4 += 4) {
      float4 fv[4], wv[8];
#pragma unroll
      for (int i = 0; i < 4; ++i) fv[i] = *(const float4*)&fL[tn + 16 * i][cc4];
#pragma unroll
      for (int j = 0; j < 8; ++j) wv[j] = *(const float4*)&wL[to + 16 * j][cc4];
#pragma unroll
      for (int i = 0; i < 4; ++i)
#pragma unroll
        for (int j = 0; j < 8; ++j) {
          acc[i][j] += fv[i].x * wv[j].x + fv[i].y * wv[j].y +
                       fv[i].z * wv[j].z + fv[i].w * wv[j].w;
        }
    }
    __syncthreads();
  }
  const int b = r0 >> 12;
  const int n0 = r0 & 4095;
#pragma unroll
  for (int i = 0; i < 4; ++i) {
    int n = n0 + tn + 16 * i;
#pragma unroll
    for (int j = 0; j < 8; ++j) {
      int o = to + 16 * j;
      out[((long)(b * NCO + o) << 12) + n] = acc[i][j] + bias[o];
    }
  }
}

// ---------- BN stats per channel over (B, N): single pass (sum, sumsq) ----------
__global__ __launch_bounds__(256) void bn_stats_k(const float* __restrict__ v,
                                                  const float* __restrict__ gamma,
                                                  const float* __restrict__ beta,
                                                  float* __restrict__ stats, int relu_in) {
  __shared__ float rs[256], rq[256];
  const int o = blockIdx.x, tid = threadIdx.x;
  float s = 0.f, ss = 0.f;
  for (int i = tid; i < NB * NN; i += 256) {
    int b = i >> 12, n = i & 4095;
    float val = v[(((long)b * NCO + o) << 12) + n];
    if (relu_in) val = fmaxf(val, 0.f);
    s += val;
    ss += val * val;
  }
  rs[tid] = s; rq[tid] = ss;
  __syncthreads();
  for (int off = 128; off > 0; off >>= 1) {
    if (tid < off) { rs[tid] += rs[tid + off]; rq[tid] += rq[tid + off]; }
    __syncthreads();
  }
  if (tid == 0) {
    float m = rs[0] * (1.f / 16384.f);
    float var = rq[0] * (1.f / 16384.f) - m * m;
    var = fmaxf(var, 0.f);
    float inv = rsqrtf(var + 1e-5f);
    stats[o] = m;
    stats[128 + o] = inv * gamma[o];
    stats[256 + o] = beta[o];
  }
}

// ---------- apply fuse BN + ReLU; write x [B,CO,N] and xt [B,N,CO] ----------
__global__ void fuse_apply_k(const float* __restrict__ xp, const float* __restrict__ stats,
                             float* __restrict__ x, float* __restrict__ xt) {
  const int stride = gridDim.x * blockDim.x;
  for (int idx = blockIdx.x * blockDim.x + threadIdx.x; idx < NB * NCO * NN; idx += stride) {
    int o = (idx >> 12) & 127;
    int b = idx >> 19;
    int n = idx & 4095;
    float v = (xp[idx] - stats[o]) * stats[128 + o] + stats[256 + o];
    v = fmaxf(v, 0.f);
    x[idx] = v;
    xt[(((long)b << 12) + n) * NCO + o] = v;
  }
}

// ---------- KNN(16): tau + BALLOT compaction (no atomics); 32 q x 8 lanes ----------
// (R11-proven structure; KCAP 96->160 to eliminate the deterministic
//  fallback tail: P(overflow) drops 6.6e-4 -> 3.5e-7 per query. LDS 74 KB
//  still = 2 blocks/CU, so occupancy unchanged.)
__global__ __launch_bounds__(256) void knn_k(const float* __restrict__ xyz1,
                                             int* __restrict__ knn) {
  __shared__ float4 sc[KCHUNK];      // 32 KB; reused as merge lists at the end
  __shared__ float bufd[32][KPAD];   // 20.1 KB
  __shared__ int bufi[32][KPAD];     // 20.1 KB
  const int b = blockIdx.y;
  const int tid = threadIdx.x;
  const int ql = tid >> 3;
  const int q = (blockIdx.x << 5) + ql;
  const int lane = tid & 7;
  const int gb = (tid & 63) - lane;  // group base lane within the wave
  const long qb = ((long)b * NN + q) * 3;
  const float qx = xyz1[qb], qy = xyz1[qb + 1], qz = xyz1[qb + 2];
  const float nq = norm3_np(qx, qy, qz);

  // ---- pass 1: tau via two independent top-2 trackers (R6-proven) ----
  float a0 = FLT_MAX, a1 = FLT_MAX, c0 = FLT_MAX, c1 = FLT_MAX;
  for (int ch = 0; ch < 2; ++ch) {
    for (int i = tid; i < KCHUNK; i += 256) {
      long base = ((long)b * NN + ch * KCHUNK + i) * 3;
      float x = xyz1[base], y = xyz1[base + 1], z = xyz1[base + 2];
      sc[i] = make_float4(x, y, z, norm3_np(x, y, z));
    }
    __syncthreads();
#pragma unroll 2
    for (int i = lane; i < KCHUNK; i += 16) {
      float4 ca = sc[i];
      float4 cb = sc[i + 8];
      float da = sqdist_np(nq, ca.w, qx, qy, qz, ca.x, ca.y, ca.z);
      float db = sqdist_np(nq, cb.w, qx, qy, qz, cb.x, cb.y, cb.z);
      float ha = fmaxf(da, a0); a0 = fminf(da, a0); a1 = fminf(ha, a1);
      float hb = fmaxf(db, c0); c0 = fminf(db, c0); c1 = fminf(hb, c1);
    }
    __syncthreads();
  }
  float tau = fminf(fmaxf(a0, c0), fminf(a1, c1));  // 2nd-smallest of union
  tau = fmaxf(tau, __shfl_xor(tau, 1, 64));
  tau = fmaxf(tau, __shfl_xor(tau, 2, 64));
  tau = fmaxf(tau, __shfl_xor(tau, 4, 64));

  // ---- pass 2: ballot-compacted survivor collection ----
  int mycnt = 0;  // survivor count for this query; uniform across its 8 lanes
  for (int ch = 0; ch < 2; ++ch) {
    for (int i = tid; i < KCHUNK; i += 256) {
      long base = ((long)b * NN + ch * KCHUNK + i) * 3;
      float x = xyz1[base], y = xyz1[base + 1], z = xyz1[base + 2];
      sc[i] = make_float4(x, y, z, norm3_np(x, y, z));
    }
    __syncthreads();
    const int cb = ch * KCHUNK;
    for (int i = lane; i < KCHUNK; i += 8) {
      float4 cc = sc[i];
      float d = sqdist_np(nq, cc.w, qx, qy, qz, cc.x, cc.y, cc.z);
      bool surv = (d <= tau);
      unsigned long long m = __ballot(surv);
      unsigned gm = (unsigned)((m >> gb) & 0xFFull);
      if (surv) {
        int pos = mycnt + __popc(gm & ((1u << lane) - 1u));
        if (pos < KCAP) { bufd[ql][pos] = d; bufi[ql][pos] = cb + i; }
      }
      mycnt += __popc(gm);
    }
    __syncthreads();
  }

  // ---- pass 3: exact stable top-16 ----
  float bd[NK]; int bi[NK];
#pragma unroll
  for (int j = 0; j < NK; ++j) { bd[j] = FLT_MAX; bi[j] = 0x7fffffff; }
  if (mycnt > KCAP) {
    // fallback: tau-guarded strict-d ladder over global (index order -> stable)
    for (int s = lane; s < NN; s += 8) {
      long base = ((long)b * NN + s) * 3;
      float x = xyz1[base], y = xyz1[base + 1], z = xyz1[base + 2];
      float d = sqdist_np(nq, norm3_np(x, y, z), qx, qy, qz, x, y, z);
      if (d <= tau) {
        float cd = d; int ci = s;
#pragma unroll
        for (int j = 0; j < NK; ++j) {
          bool lt = cd < bd[j];
          float dmin = fminf(cd, bd[j]);
          float dmax = fmaxf(cd, bd[j]);
          int imin = lt ? ci : bi[j];
          int imax = lt ? bi[j] : ci;
          bd[j] = dmin; bi[j] = imin; cd = dmax; ci = imax;
        }
      }
    }
  } else {
    for (int j0 = lane; j0 < mycnt; j0 += 8) {
      float cd = bufd[ql][j0]; int ci = bufi[ql][j0];
#pragma unroll
      for (int j = 0; j < NK; ++j) {
        bool lt = (cd < bd[j]) || (cd == bd[j] && ci < bi[j]);  // lex (d, idx)
        float nd = lt ? cd : bd[j];
        float xd = lt ? bd[j] : cd;
        int ni = lt ? ci : bi[j];
        int xi = lt ? bi[j] : ci;
        bd[j] = nd; bi[j] = ni; cd = xd; ci = xi;
      }
    }
  }
  __syncthreads();  // staging LDS dead; reuse sc for merge lists

  float* md = (float*)sc;        // 256*16 floats = 16 KB
  int* mi = (int*)sc + 4096;     // 256*16 ints  = 16 KB
#pragma unroll
  for (int j = 0; j < NK; ++j) { md[tid * NK + j] = bd[j]; mi[tid * NK + j] = bi[j]; }
  __syncthreads();
  if (lane == 0) {
    int p0 = 0, p1 = 0, p2 = 0, p3 = 0, p4 = 0, p5 = 0, p6 = 0, p7 = 0;
    long obase = ((long)b * NN + q) * NK;
    for (int j = 0; j < NK; ++j) {
      float bv = FLT_MAX; int bidx = 0x7fffffff; int bl = 0;
#define KNN_CAND(l, pl)                                                      \
      {                                                                      \
        float t = (pl < NK) ? md[(tid + l) * NK + pl] : FLT_MAX;             \
        int ti = (pl < NK) ? mi[(tid + l) * NK + pl] : 0x7fffffff;           \
        if (t < bv || (t == bv && ti < bidx)) { bv = t; bidx = ti; bl = l; } \
      }
      KNN_CAND(0, p0) KNN_CAND(1, p1) KNN_CAND(2, p2) KNN_CAND(3, p3)
      KNN_CAND(4, p4) KNN_CAND(5, p5) KNN_CAND(6, p6) KNN_CAND(7, p7)
#undef KNN_CAND
      knn[obase + j] = bidx;
      p0 += (bl == 0); p1 += (bl == 1); p2 += (bl == 2); p3 += (bl == 3);
      p4 += (bl == 4); p5 += (bl == 5); p6 += (bl == 6); p7 += (bl == 7);
    }
  }
}

// ---------- Laplacian gather: dxt[q][o] = sum_k xt[nbr_k][o] - xt[q][o] ----------
__global__ __launch_bounds__(256) void lap_gather_k(const float* __restrict__ xt,
                                                    const int* __restrict__ knn,
                                                    float* __restrict__ dxt) {
  const int q = (blockIdx.x << 1) + (threadIdx.x >> 7);
  const int o = threadIdx.x & 127;
  const int b = q >> 12;
  const int* kid = knn + (long)q * NK;
  const long bb = ((long)b << 12) * NCO;
  float s = 0.f;
#pragma unroll
  for (int k = 0; k < NK; ++k) {
    int m = kid[k];
    s += xt[bb + (long)m * NCO + o];
  }
  dxt[(long)q * NCO + o] = s - xt[(long)q * NCO + o];
}

// ---------- final: out = x + BN(relu(h_pre)) ----------
__global__ void final_k(const float* __restrict__ x, const float* __restrict__ hp,
                        const float* __restrict__ stats, float* __restrict__ out) {
  const int stride = gridDim.x * blockDim.x;
  for (int idx = blockIdx.x * blockDim.x + threadIdx.x; idx < NB * NCO * NN; idx += stride) {
    int o = (idx >> 12) & 127;
    float r = fmaxf(hp[idx], 0.f);
    out[idx] = x[idx] + (r - stats[o]) * stats[128 + o] + stats[256 + o];
  }
}

extern "C" void kernel_launch(void* const* d_in, const int* in_sizes, int n_in,
                              void* d_out, int out_size, void* d_ws, size_t ws_size,
                              hipStream_t stream) {
  const float* xyz1 = (const float*)d_in[0];
  const float* xyz2 = (const float*)d_in[1];
  const float* points1 = (const float*)d_in[2];
  const float* points2 = (const float*)d_in[3];
  const float* fuse_w = (const float*)d_in[4];
  const float* fuse_b = (const float*)d_in[5];
  const float* fuse_g = (const float*)d_in[6];
  const float* fuse_be = (const float*)d_in[7];
  const float* lu_w = (const float*)d_in[8];
  const float* lu_b = (const float*)d_in[9];
  const float* lu_g = (const float*)d_in[10];
  const float* lu_be = (const float*)d_in[11];
  (void)in_sizes; (void)n_in; (void)out_size; (void)ws_size;

  char* ws = (char*)d_ws;
  float* p2t = (float*)(ws);                   // 4,194,304 B  [B,S,C2]
  float* wW = (float*)(ws + 4194304);          //   196,608 B  [B,N,3]
  int* wIdx = (int*)(ws + 4390912);            //   196,608 B
  float* st1 = (float*)(ws + 4587520);         //     1,536 B
  float* st2 = (float*)(ws + 4589056);         //     1,536 B
  int* knn = (int*)(ws + 4590592);             // 1,048,576 B  [B,N,16]
  float* nt = (float*)(ws + 5639168);          // 25,165,824 B [B*N,384]
  float* xp = (float*)(ws + 30804992);         // 8,388,608 B  [B,CO,N]
  float* x = (float*)(ws + 39193600);          // 8,388,608 B  [B,CO,N]
  // nt is dead after the fuse GEMM -> reuse its 25.1 MB for xt/dxt/hp
  float* xt = nt;                  // [B,N,CO]
  float* dxt = nt + 2097152;       // [B*N,CO]
  float* hp = nt + 4194304;        // [B,CO,N]

  dim3 tb(32, 8);
  transpose_k<<<dim3(32, 8, NB), tb, 0, stream>>>(points2, p2t, 256, 1024, 262144L, 262144L, 256);
  transpose_k<<<dim3(128, 4, NB), tb, 0, stream>>>(points1, nt, 128, 4096, 524288L, 1572864L, 384);
  interp_top3_k<<<dim3(128, NB), 256, 0, stream>>>(xyz1, xyz2, wW, wIdx);
  interp_fill_k<<<8192, 256, 0, stream>>>(p2t, wW, wIdx, nt);
  gemm_bias_k<NCC><<<256, 256, 0, stream>>>(nt, fuse_w, fuse_b, xp);
  bn_stats_k<<<128, 256, 0, stream>>>(xp, fuse_g, fuse_be, st1, 0);
  fuse_apply_k<<<2048, 256, 0, stream>>>(xp, st1, x, xt);
  knn_k<<<dim3(128, NB), 256, 0, stream>>>(xyz1, knn);
  lap_gather_k<<<8192, 256, 0, stream>>>(xt, knn, dxt);
  gemm_bias_k<NCO><<<256, 256, 0, stream>>>(dxt, lu_w, lu_b, hp);
  bn_stats_k<<<128, 256, 0, stream>>>(hp, lu_g, lu_be, st2, 1);
  final_k<<<2048, 256, 0, stream>>>(x, hp, st2, (float*)d_out);
}

// Round 14
// 262.386 us; speedup vs baseline: 2.5997x; 1.0915x over previous
//
#include <hip/hip_runtime.h>
#include <cfloat>

#define NB 4
#define NN 4096
#define NS 1024
#define NC1 128
#define NC2 256
#define NCO 128
#define NCC 384
#define NK 16
#define KCHUNK 2048
#define KCAP 160
#define KPAD 161

// NOTE on numerics: the reference computes squared distances in the EXPANDED
// form ||a||^2 + ||b||^2 - 2 a.b (see _sqdist). Top-k selections sit on
// near-ties whose resolution depends on the exact fp bits, so both selection
// kernels below replicate numpy's op order exactly with non-contractible
// __fmul_rn/__fadd_rn/__fsub_rn (no FMA fusion allowed).

__device__ __forceinline__ float norm3_np(float x, float y, float z) {
  return __fadd_rn(__fadd_rn(__fmul_rn(x, x), __fmul_rn(y, y)), __fmul_rn(z, z));
}

__device__ __forceinline__ float sqdist_np(float nq, float ns,
                                           float qx, float qy, float qz,
                                           float sx, float sy, float sz) {
  float dot = __fadd_rn(__fadd_rn(__fmul_rn(qx, sx), __fmul_rn(qy, sy)),
                        __fmul_rn(qz, sz));
  return __fsub_rn(__fadd_rn(nq, ns), __fmul_rn(2.0f, dot));
}

// ---------- generic 32x32 LDS-tiled transpose with strided output ----------
__global__ void transpose_k(const float* __restrict__ in, float* __restrict__ out,
                            int rows_in, int cols_in, long in_bs, long out_bs, int out_rs) {
  __shared__ float tile[32][33];
  const int b = blockIdx.z;
  const int c0 = blockIdx.x * 32, r0 = blockIdx.y * 32;
  const float* ib = in + (long)b * in_bs;
  float* ob = out + (long)b * out_bs;
#pragma unroll
  for (int k = 0; k < 32; k += 8) {
    tile[threadIdx.y + k][threadIdx.x] =
        ib[(long)(r0 + threadIdx.y + k) * cols_in + c0 + threadIdx.x];
  }
  __syncthreads();
#pragma unroll
  for (int k = 0; k < 32; k += 8) {
    ob[(long)(c0 + threadIdx.y + k) * out_rs + (r0 + threadIdx.x)] =
        tile[threadIdx.x][threadIdx.y + k];
  }
}

// ---------- 3-point interpolation: top-3 LARGEST distances (faithful) ----------
// block: 256 threads = 32 queries x 8 lanes; grid (N/32, B)
__global__ __launch_bounds__(256) void interp_top3_k(const float* __restrict__ xyz1,
                                                     const float* __restrict__ xyz2,
                                                     float* __restrict__ wW,
                                                     int* __restrict__ wIdx) {
  __shared__ float sx[NS], sy[NS], sz[NS], sn[NS];
  __shared__ float md[256 * 3];
  __shared__ int mi[256 * 3];
  const int b = blockIdx.y;
  const int tid = threadIdx.x;
  for (int i = tid; i < NS; i += 256) {
    long base = ((long)b * NS + i) * 3;
    float x = xyz2[base], y = xyz2[base + 1], z = xyz2[base + 2];
    sx[i] = x; sy[i] = y; sz[i] = z;
    sn[i] = norm3_np(x, y, z);
  }
  __syncthreads();
  const int q = (blockIdx.x << 5) + (tid >> 3);
  const int lane = tid & 7;
  long qb = ((long)b * NN + q) * 3;
  const float qx = xyz1[qb], qy = xyz1[qb + 1], qz = xyz1[qb + 2];
  const float nq = norm3_np(qx, qy, qz);
  float bd[3] = {-FLT_MAX, -FLT_MAX, -FLT_MAX};
  int bi[3] = {0x7fffffff, 0x7fffffff, 0x7fffffff};
  for (int s = lane; s < NS; s += 8) {
    float d = sqdist_np(nq, sn[s], qx, qy, qz, sx[s], sy[s], sz[s]);
    float cd = d; int ci = s;
#pragma unroll
    for (int j = 0; j < 3; ++j) {
      bool gt = cd > bd[j];                  // strict: tie keeps earlier (lower idx)
      float f = fmaxf(cd, bd[j]);
      float bk = fminf(cd, bd[j]);
      int fi = gt ? ci : bi[j];
      int ki = gt ? bi[j] : ci;
      bd[j] = f; bi[j] = fi; cd = bk; ci = ki;
    }
  }
#pragma unroll
  for (int j = 0; j < 3; ++j) { md[tid * 3 + j] = bd[j]; mi[tid * 3 + j] = bi[j]; }
  __syncthreads();
  if (lane == 0) {
    int p0 = 0, p1 = 0, p2 = 0, p3 = 0, p4 = 0, p5 = 0, p6 = 0, p7 = 0;
    float od[3]; int oi[3];
#pragma unroll
    for (int j = 0; j < 3; ++j) {
      float bv = -FLT_MAX; int bidx = 0x7fffffff; int bl = 0;
#define ITOP_CAND(l, pl)                                                     \
      {                                                                      \
        float t = (pl < 3) ? md[(tid + l) * 3 + pl] : -FLT_MAX;              \
        int ti = (pl < 3) ? mi[(tid + l) * 3 + pl] : 0x7fffffff;             \
        if (t > bv || (t == bv && ti < bidx)) { bv = t; bidx = ti; bl = l; } \
      }
      ITOP_CAND(0, p0) ITOP_CAND(1, p1) ITOP_CAND(2, p2) ITOP_CAND(3, p3)
      ITOP_CAND(4, p4) ITOP_CAND(5, p5) ITOP_CAND(6, p6) ITOP_CAND(7, p7)
#undef ITOP_CAND
      od[j] = bv; oi[j] = bidx;
      p0 += (bl == 0); p1 += (bl == 1); p2 += (bl == 2); p3 += (bl == 3);
      p4 += (bl == 4); p5 += (bl == 5); p6 += (bl == 6); p7 += (bl == 7);
    }
    float r0 = 1.f / (od[0] + 1e-8f);
    float r1 = 1.f / (od[1] + 1e-8f);
    float r2 = 1.f / (od[2] + 1e-8f);
    float sR = __fadd_rn(__fadd_rn(r0, r1), r2);
    long obase = ((long)b * NN + q) * 3;
    wW[obase + 0] = r0 / sR; wW[obase + 1] = r1 / sR; wW[obase + 2] = r2 / sR;
    wIdx[obase + 0] = oi[0]; wIdx[obase + 1] = oi[1]; wIdx[obase + 2] = oi[2];
  }
}

// ---------- fill interp channels of nt (cols 128..383) ----------
__global__ __launch_bounds__(256) void interp_fill_k(const float* __restrict__ p2t,
                                                     const float* __restrict__ wW,
                                                     const int* __restrict__ wIdx,
                                                     float* __restrict__ nt) {
  const int q = (blockIdx.x << 1) + (threadIdx.x >> 7);
  const int co = threadIdx.x & 127;
  const int b = q >> 12;
  long wb = (long)q * 3;
  float w0 = wW[wb], w1 = wW[wb + 1], w2 = wW[wb + 2];
  int i0 = wIdx[wb], i1 = wIdx[wb + 1], i2 = wIdx[wb + 2];
  const float* r0 = p2t + ((long)(b << 10) + i0) * NC2;
  const float* r1 = p2t + ((long)(b << 10) + i1) * NC2;
  const float* r2 = p2t + ((long)(b << 10) + i2) * NC2;
  float* orow = nt + (long)q * NCC + NC1;
#pragma unroll
  for (int h = 0; h < 2; ++h) {
    int c = co + 128 * h;
    orow[c] = w0 * r0[c] + w1 * r1[c] + w2 * r2[c];
  }
}

// ---------- f32 tiled GEMM: 64 rows x 64 output channels per block ----------
// grid (M/64, CO/64) = (256, 2) -> 512 blocks = 2 blocks/CU = 2 waves/SIMD.
// Total W-staging traffic unchanged vs 64x128 (each block stages only its
// 64-channel half) -- avoids R10's doubled-W-traffic mistake.
template <int C>
__global__ __launch_bounds__(256) void gemm_bias_k(const float* __restrict__ feat,
                                                   const float* __restrict__ W,
                                                   const float* __restrict__ bias,
                                                   float* __restrict__ out) {
  __shared__ float fL[64][36];
  __shared__ float wL[64][36];
  const int r0 = blockIdx.x * 64;
  const int ob = blockIdx.y * 64;
  const int tid = threadIdx.x;
  const int tn = tid & 15;
  const int to = tid >> 4;
  float acc[4][4];
#pragma unroll
  for (int i = 0; i < 4; ++i)
#pragma unroll
    for (int j = 0; j < 4; ++j) acc[i][j] = 0.f;

  for (int c0 = 0; c0 < C; c0 += 32) {
#pragma unroll
    for (int k = 0; k < 8; ++k) {
      int e = tid + 256 * k;
      int rr = e >> 5, cc = e & 31;
      fL[rr][cc] = feat[(long)(r0 + rr) * C + c0 + cc];
    }
#pragma unroll
    for (int k = 0; k < 8; ++k) {
      int e = tid + 256 * k;
      int rr = e >> 5, cc = e & 31;
      wL[rr][cc] = W[(long)(ob + rr) * C + c0 + cc];
    }
    __syncthreads();
#pragma unroll
    for (int cc4 = 0; cc4 < 32; cc4 += 4) {
      float4 fv[4], wv[4];
#pragma unroll
      for (int i = 0; i < 4; ++i) fv[i] = *(const float4*)&fL[tn + 16 * i][cc4];
#pragma unroll
      for (int j = 0; j < 4; ++j) wv[j] = *(const float4*)&wL[to + 16 * j][cc4];
#pragma unroll
      for (int i = 0; i < 4; ++i)
#pragma unroll
        for (int j = 0; j < 4; ++j) {
          acc[i][j] += fv[i].x * wv[j].x + fv[i].y * wv[j].y +
                       fv[i].z * wv[j].z + fv[i].w * wv[j].w;
        }
    }
    __syncthreads();
  }
  const int b = r0 >> 12;
  const int n0 = r0 & 4095;
#pragma unroll
  for (int i = 0; i < 4; ++i) {
    int n = n0 + tn + 16 * i;
#pragma unroll
    for (int j = 0; j < 4; ++j) {
      int o = ob + to + 16 * j;
      out[((long)(b * NCO + o) << 12) + n] = acc[i][j] + bias[o];
    }
  }
}

// ---------- BN stats per channel over (B, N): single pass (sum, sumsq) ----------
__global__ __launch_bounds__(256) void bn_stats_k(const float* __restrict__ v,
                                                  const float* __restrict__ gamma,
                                                  const float* __restrict__ beta,
                                                  float* __restrict__ stats, int relu_in) {
  __shared__ float rs[256], rq[256];
  const int o = blockIdx.x, tid = threadIdx.x;
  float s = 0.f, ss = 0.f;
  for (int i = tid; i < NB * NN; i += 256) {
    int b = i >> 12, n = i & 4095;
    float val = v[(((long)b * NCO + o) << 12) + n];
    if (relu_in) val = fmaxf(val, 0.f);
    s += val;
    ss += val * val;
  }
  rs[tid] = s; rq[tid] = ss;
  __syncthreads();
  for (int off = 128; off > 0; off >>= 1) {
    if (tid < off) { rs[tid] += rs[tid + off]; rq[tid] += rq[tid + off]; }
    __syncthreads();
  }
  if (tid == 0) {
    float m = rs[0] * (1.f / 16384.f);
    float var = rq[0] * (1.f / 16384.f) - m * m;
    var = fmaxf(var, 0.f);
    float inv = rsqrtf(var + 1e-5f);
    stats[o] = m;
    stats[128 + o] = inv * gamma[o];
    stats[256 + o] = beta[o];
  }
}

// ---------- apply fuse BN + ReLU; write x [B,CO,N] and xt [B,N,CO] ----------
__global__ void fuse_apply_k(const float* __restrict__ xp, const float* __restrict__ stats,
                             float* __restrict__ x, float* __restrict__ xt) {
  const int stride = gridDim.x * blockDim.x;
  for (int idx = blockIdx.x * blockDim.x + threadIdx.x; idx < NB * NCO * NN; idx += stride) {
    int o = (idx >> 12) & 127;
    int b = idx >> 19;
    int n = idx & 4095;
    float v = (xp[idx] - stats[o]) * stats[128 + o] + stats[256 + o];
    v = fmaxf(v, 0.f);
    x[idx] = v;
    xt[(((long)b << 12) + n) * NCO + o] = v;
  }
}

// ---------- KNN(16): tau + BALLOT compaction (no atomics); 32 q x 8 lanes ----------
// R11-proven structure; pass 2 now processes 2 candidates/iteration (2
// independent distances + 2 ballots) for ILP. Buffer order changes within an
// iteration but pass 3's lex-(d,idx) ladder is order-independent -> output
// bit-identical. KCAP 160: P(overflow) ~3.5e-7/query.
__global__ __launch_bounds__(256) void knn_k(const float* __restrict__ xyz1,
                                             int* __restrict__ knn) {
  __shared__ float4 sc[KCHUNK];      // 32 KB; reused as merge lists at the end
  __shared__ float bufd[32][KPAD];   // 20.1 KB
  __shared__ int bufi[32][KPAD];     // 20.1 KB
  const int b = blockIdx.y;
  const int tid = threadIdx.x;
  const int ql = tid >> 3;
  const int q = (blockIdx.x << 5) + ql;
  const int lane = tid & 7;
  const int gb = (tid & 63) - lane;  // group base lane within the wave
  const long qb = ((long)b * NN + q) * 3;
  const float qx = xyz1[qb], qy = xyz1[qb + 1], qz = xyz1[qb + 2];
  const float nq = norm3_np(qx, qy, qz);

  // ---- pass 1: tau via two independent top-2 trackers (R6-proven) ----
  float a0 = FLT_MAX, a1 = FLT_MAX, c0 = FLT_MAX, c1 = FLT_MAX;
  for (int ch = 0; ch < 2; ++ch) {
    for (int i = tid; i < KCHUNK; i += 256) {
      long base = ((long)b * NN + ch * KCHUNK + i) * 3;
      float x = xyz1[base], y = xyz1[base + 1], z = xyz1[base + 2];
      sc[i] = make_float4(x, y, z, norm3_np(x, y, z));
    }
    __syncthreads();
#pragma unroll 2
    for (int i = lane; i < KCHUNK; i += 16) {
      float4 ca = sc[i];
      float4 cb = sc[i + 8];
      float da = sqdist_np(nq, ca.w, qx, qy, qz, ca.x, ca.y, ca.z);
      float db = sqdist_np(nq, cb.w, qx, qy, qz, cb.x, cb.y, cb.z);
      float ha = fmaxf(da, a0); a0 = fminf(da, a0); a1 = fminf(ha, a1);
      float hb = fmaxf(db, c0); c0 = fminf(db, c0); c1 = fminf(hb, c1);
    }
    __syncthreads();
  }
  float tau = fminf(fmaxf(a0, c0), fminf(a1, c1));  // 2nd-smallest of union
  tau = fmaxf(tau, __shfl_xor(tau, 1, 64));
  tau = fmaxf(tau, __shfl_xor(tau, 2, 64));
  tau = fmaxf(tau, __shfl_xor(tau, 4, 64));

  // ---- pass 2: ballot-compacted survivor collection (2-way ILP) ----
  int mycnt = 0;  // survivor count for this query; uniform across its 8 lanes
  for (int ch = 0; ch < 2; ++ch) {
    for (int i = tid; i < KCHUNK; i += 256) {
      long base = ((long)b * NN + ch * KCHUNK + i) * 3;
      float x = xyz1[base], y = xyz1[base + 1], z = xyz1[base + 2];
      sc[i] = make_float4(x, y, z, norm3_np(x, y, z));
    }
    __syncthreads();
    const int cb = ch * KCHUNK;
    for (int i = lane; i < KCHUNK; i += 16) {
      float4 v0 = sc[i];
      float4 v1 = sc[i + 8];
      float d0 = sqdist_np(nq, v0.w, qx, qy, qz, v0.x, v0.y, v0.z);
      float d1 = sqdist_np(nq, v1.w, qx, qy, qz, v1.x, v1.y, v1.z);
      bool s0 = (d0 <= tau);
      bool s1 = (d1 <= tau);
      unsigned long long m0 = __ballot(s0);
      unsigned long long m1 = __ballot(s1);
      unsigned g0 = (unsigned)((m0 >> gb) & 0xFFull);
      unsigned g1 = (unsigned)((m1 >> gb) & 0xFFull);
      if (s0) {
        int pos = mycnt + __popc(g0 & ((1u << lane) - 1u));
        if (pos < KCAP) { bufd[ql][pos] = d0; bufi[ql][pos] = cb + i; }
      }
      if (s1) {
        int pos = mycnt + __popc(g0) + __popc(g1 & ((1u << lane) - 1u));
        if (pos < KCAP) { bufd[ql][pos] = d1; bufi[ql][pos] = cb + i + 8; }
      }
      mycnt += __popc(g0) + __popc(g1);
    }
    __syncthreads();
  }

  // ---- pass 3: exact stable top-16 ----
  float bd[NK]; int bi[NK];
#pragma unroll
  for (int j = 0; j < NK; ++j) { bd[j] = FLT_MAX; bi[j] = 0x7fffffff; }
  if (mycnt > KCAP) {
    // fallback: tau-guarded strict-d ladder over global (index order -> stable)
    for (int s = lane; s < NN; s += 8) {
      long base = ((long)b * NN + s) * 3;
      float x = xyz1[base], y = xyz1[base + 1], z = xyz1[base + 2];
      float d = sqdist_np(nq, norm3_np(x, y, z), qx, qy, qz, x, y, z);
      if (d <= tau) {
        float cd = d; int ci = s;
#pragma unroll
        for (int j = 0; j < NK; ++j) {
          bool lt = cd < bd[j];
          float dmin = fminf(cd, bd[j]);
          float dmax = fmaxf(cd, bd[j]);
          int imin = lt ? ci : bi[j];
          int imax = lt ? bi[j] : ci;
          bd[j] = dmin; bi[j] = imin; cd = dmax; ci = imax;
        }
      }
    }
  } else {
    for (int j0 = lane; j0 < mycnt; j0 += 8) {
      float cd = bufd[ql][j0]; int ci = bufi[ql][j0];
#pragma unroll
      for (int j = 0; j < NK; ++j) {
        bool lt = (cd < bd[j]) || (cd == bd[j] && ci < bi[j]);  // lex (d, idx)
        float nd = lt ? cd : bd[j];
        float xd = lt ? bd[j] : cd;
        int ni = lt ? ci : bi[j];
        int xi = lt ? bi[j] : ci;
        bd[j] = nd; bi[j] = ni; cd = xd; ci = xi;
      }
    }
  }
  __syncthreads();  // staging LDS dead; reuse sc for merge lists

  float* md = (float*)sc;        // 256*16 floats = 16 KB
  int* mi = (int*)sc + 4096;     // 256*16 ints  = 16 KB
#pragma unroll
  for (int j = 0; j < NK; ++j) { md[tid * NK + j] = bd[j]; mi[tid * NK + j] = bi[j]; }
  __syncthreads();
  if (lane == 0) {
    int p0 = 0, p1 = 0, p2 = 0, p3 = 0, p4 = 0, p5 = 0, p6 = 0, p7 = 0;
    long obase = ((long)b * NN + q) * NK;
    for (int j = 0; j < NK; ++j) {
      float bv = FLT_MAX; int bidx = 0x7fffffff; int bl = 0;
#define KNN_CAND(l, pl)                                                      \
      {                                                                      \
        float t = (pl < NK) ? md[(tid + l) * NK + pl] : FLT_MAX;             \
        int ti = (pl < NK) ? mi[(tid + l) * NK + pl] : 0x7fffffff;           \
        if (t < bv || (t == bv && ti < bidx)) { bv = t; bidx = ti; bl = l; } \
      }
      KNN_CAND(0, p0) KNN_CAND(1, p1) KNN_CAND(2, p2) KNN_CAND(3, p3)
      KNN_CAND(4, p4) KNN_CAND(5, p5) KNN_CAND(6, p6) KNN_CAND(7, p7)
#undef KNN_CAND
      knn[obase + j] = bidx;
      p0 += (bl == 0); p1 += (bl == 1); p2 += (bl == 2); p3 += (bl == 3);
      p4 += (bl == 4); p5 += (bl == 5); p6 += (bl == 6); p7 += (bl == 7);
    }
  }
}

// ---------- Laplacian gather: dxt[q][o] = sum_k xt[nbr_k][o] - xt[q][o] ----------
__global__ __launch_bounds__(256) void lap_gather_k(const float* __restrict__ xt,
                                                    const int* __restrict__ knn,
                                                    float* __restrict__ dxt) {
  const int q = (blockIdx.x << 1) + (threadIdx.x >> 7);
  const int o = threadIdx.x & 127;
  const int b = q >> 12;
  const int* kid = knn + (long)q * NK;
  const long bb = ((long)b << 12) * NCO;
  float s = 0.f;
#pragma unroll
  for (int k = 0; k < NK; ++k) {
    int m = kid[k];
    s += xt[bb + (long)m * NCO + o];
  }
  dxt[(long)q * NCO + o] = s - xt[(long)q * NCO + o];
}

// ---------- final: out = x + BN(relu(h_pre)) ----------
__global__ void final_k(const float* __restrict__ x, const float* __restrict__ hp,
                        const float* __restrict__ stats, float* __restrict__ out) {
  const int stride = gridDim.x * blockDim.x;
  for (int idx = blockIdx.x * blockDim.x + threadIdx.x; idx < NB * NCO * NN; idx += stride) {
    int o = (idx >> 12) & 127;
    float r = fmaxf(hp[idx], 0.f);
    out[idx] = x[idx] + (r - stats[o]) * stats[128 + o] + stats[256 + o];
  }
}

extern "C" void kernel_launch(void* const* d_in, const int* in_sizes, int n_in,
                              void* d_out, int out_size, void* d_ws, size_t ws_size,
                              hipStream_t stream) {
  const float* xyz1 = (const float*)d_in[0];
  const float* xyz2 = (const float*)d_in[1];
  const float* points1 = (const float*)d_in[2];
  const float* points2 = (const float*)d_in[3];
  const float* fuse_w = (const float*)d_in[4];
  const float* fuse_b = (const float*)d_in[5];
  const float* fuse_g = (const float*)d_in[6];
  const float* fuse_be = (const float*)d_in[7];
  const float* lu_w = (const float*)d_in[8];
  const float* lu_b = (const float*)d_in[9];
  const float* lu_g = (const float*)d_in[10];
  const float* lu_be = (const float*)d_in[11];
  (void)in_sizes; (void)n_in; (void)out_size; (void)ws_size;

  char* ws = (char*)d_ws;
  float* p2t = (float*)(ws);                   // 4,194,304 B  [B,S,C2]
  float* wW = (float*)(ws + 4194304);          //   196,608 B  [B,N,3]
  int* wIdx = (int*)(ws + 4390912);            //   196,608 B
  float* st1 = (float*)(ws + 4587520);         //     1,536 B
  float* st2 = (float*)(ws + 4589056);         //     1,536 B
  int* knn = (int*)(ws + 4590592);             // 1,048,576 B  [B,N,16]
  float* nt = (float*)(ws + 5639168);          // 25,165,824 B [B*N,384]
  float* xp = (float*)(ws + 30804992);         // 8,388,608 B  [B,CO,N]
  float* x = (float*)(ws + 39193600);          // 8,388,608 B  [B,CO,N]
  // nt is dead after the fuse GEMM -> reuse its 25.1 MB for xt/dxt/hp
  float* xt = nt;                  // [B,N,CO]
  float* dxt = nt + 2097152;       // [B*N,CO]
  float* hp = nt + 4194304;        // [B,CO,N]

  dim3 tb(32, 8);
  transpose_k<<<dim3(32, 8, NB), tb, 0, stream>>>(points2, p2t, 256, 1024, 262144L, 262144L, 256);
  transpose_k<<<dim3(128, 4, NB), tb, 0, stream>>>(points1, nt, 128, 4096, 524288L, 1572864L, 384);
  interp_top3_k<<<dim3(128, NB), 256, 0, stream>>>(xyz1, xyz2, wW, wIdx);
  interp_fill_k<<<8192, 256, 0, stream>>>(p2t, wW, wIdx, nt);
  gemm_bias_k<NCC><<<dim3(256, 2), 256, 0, stream>>>(nt, fuse_w, fuse_b, xp);
  bn_stats_k<<<128, 256, 0, stream>>>(xp, fuse_g, fuse_be, st1, 0);
  fuse_apply_k<<<2048, 256, 0, stream>>>(xp, st1, x, xt);
  knn_k<<<dim3(128, NB), 256, 0, stream>>>(xyz1, knn);
  lap_gather_k<<<8192, 256, 0, stream>>>(xt, knn, dxt);
  gemm_bias_k<NCO><<<dim3(256, 2), 256, 0, stream>>>(dxt, lu_w, lu_b, hp);
  bn_stats_k<<<128, 256, 0, stream>>>(hp, lu_g, lu_be, st2, 1);
  final_k<<<2048, 256, 0, stream>>>(x, hp, st2, (float*)d_out);
}

// Round 15
// 258.296 us; speedup vs baseline: 2.6409x; 1.0158x over previous
//
#include <hip/hip_runtime.h>
#include <cfloat>

#define NB 4
#define NN 4096
#define NS 1024
#define NC1 128
#define NC2 256
#define NCO 128
#define NCC 384
#define NK 16
#define KCHUNK 2048
#define KCAP 160
#define KPAD 161

// NOTE on numerics: the reference computes squared distances in the EXPANDED
// form ||a||^2 + ||b||^2 - 2 a.b (see _sqdist). Top-k selections sit on
// near-ties whose resolution depends on the exact fp bits, so both selection
// kernels below replicate numpy's op order exactly with non-contractible
// __fmul_rn/__fadd_rn/__fsub_rn (no FMA fusion allowed).

__device__ __forceinline__ float norm3_np(float x, float y, float z) {
  return __fadd_rn(__fadd_rn(__fmul_rn(x, x), __fmul_rn(y, y)), __fmul_rn(z, z));
}

__device__ __forceinline__ float sqdist_np(float nq, float ns,
                                           float qx, float qy, float qz,
                                           float sx, float sy, float sz) {
  float dot = __fadd_rn(__fadd_rn(__fmul_rn(qx, sx), __fmul_rn(qy, sy)),
                        __fmul_rn(qz, sz));
  return __fsub_rn(__fadd_rn(nq, ns), __fmul_rn(2.0f, dot));
}

// ---------- generic 32x32 LDS-tiled transpose with strided output ----------
__global__ void transpose_k(const float* __restrict__ in, float* __restrict__ out,
                            int rows_in, int cols_in, long in_bs, long out_bs, int out_rs) {
  __shared__ float tile[32][33];
  const int b = blockIdx.z;
  const int c0 = blockIdx.x * 32, r0 = blockIdx.y * 32;
  const float* ib = in + (long)b * in_bs;
  float* ob = out + (long)b * out_bs;
#pragma unroll
  for (int k = 0; k < 32; k += 8) {
    tile[threadIdx.y + k][threadIdx.x] =
        ib[(long)(r0 + threadIdx.y + k) * cols_in + c0 + threadIdx.x];
  }
  __syncthreads();
#pragma unroll
  for (int k = 0; k < 32; k += 8) {
    ob[(long)(c0 + threadIdx.y + k) * out_rs + (r0 + threadIdx.x)] =
        tile[threadIdx.x][threadIdx.y + k];
  }
}

// ---------- 3-point interpolation: top-3 LARGEST distances (faithful) ----------
// block: 256 threads = 32 queries x 8 lanes; grid (N/32, B)
__global__ __launch_bounds__(256) void interp_top3_k(const float* __restrict__ xyz1,
                                                     const float* __restrict__ xyz2,
                                                     float* __restrict__ wW,
                                                     int* __restrict__ wIdx) {
  __shared__ float sx[NS], sy[NS], sz[NS], sn[NS];
  __shared__ float md[256 * 3];
  __shared__ int mi[256 * 3];
  const int b = blockIdx.y;
  const int tid = threadIdx.x;
  for (int i = tid; i < NS; i += 256) {
    long base = ((long)b * NS + i) * 3;
    float x = xyz2[base], y = xyz2[base + 1], z = xyz2[base + 2];
    sx[i] = x; sy[i] = y; sz[i] = z;
    sn[i] = norm3_np(x, y, z);
  }
  __syncthreads();
  const int q = (blockIdx.x << 5) + (tid >> 3);
  const int lane = tid & 7;
  long qb = ((long)b * NN + q) * 3;
  const float qx = xyz1[qb], qy = xyz1[qb + 1], qz = xyz1[qb + 2];
  const float nq = norm3_np(qx, qy, qz);
  float bd[3] = {-FLT_MAX, -FLT_MAX, -FLT_MAX};
  int bi[3] = {0x7fffffff, 0x7fffffff, 0x7fffffff};
  for (int s = lane; s < NS; s += 8) {
    float d = sqdist_np(nq, sn[s], qx, qy, qz, sx[s], sy[s], sz[s]);
    if (d > bd[2]) {   // guard: ladder is a no-op when d <= bd[2] (identical result)
      float cd = d; int ci = s;
#pragma unroll
      for (int j = 0; j < 3; ++j) {
        bool gt = cd > bd[j];                // strict: tie keeps earlier (lower idx)
        float f = fmaxf(cd, bd[j]);
        float bk = fminf(cd, bd[j]);
        int fi = gt ? ci : bi[j];
        int ki = gt ? bi[j] : ci;
        bd[j] = f; bi[j] = fi; cd = bk; ci = ki;
      }
    }
  }
#pragma unroll
  for (int j = 0; j < 3; ++j) { md[tid * 3 + j] = bd[j]; mi[tid * 3 + j] = bi[j]; }
  __syncthreads();
  if (lane == 0) {
    int p0 = 0, p1 = 0, p2 = 0, p3 = 0, p4 = 0, p5 = 0, p6 = 0, p7 = 0;
    float od[3]; int oi[3];
#pragma unroll
    for (int j = 0; j < 3; ++j) {
      float bv = -FLT_MAX; int bidx = 0x7fffffff; int bl = 0;
#define ITOP_CAND(l, pl)                                                     \
      {                                                                      \
        float t = (pl < 3) ? md[(tid + l) * 3 + pl] : -FLT_MAX;              \
        int ti = (pl < 3) ? mi[(tid + l) * 3 + pl] : 0x7fffffff;             \
        if (t > bv || (t == bv && ti < bidx)) { bv = t; bidx = ti; bl = l; } \
      }
      ITOP_CAND(0, p0) ITOP_CAND(1, p1) ITOP_CAND(2, p2) ITOP_CAND(3, p3)
      ITOP_CAND(4, p4) ITOP_CAND(5, p5) ITOP_CAND(6, p6) ITOP_CAND(7, p7)
#undef ITOP_CAND
      od[j] = bv; oi[j] = bidx;
      p0 += (bl == 0); p1 += (bl == 1); p2 += (bl == 2); p3 += (bl == 3);
      p4 += (bl == 4); p5 += (bl == 5); p6 += (bl == 6); p7 += (bl == 7);
    }
    float r0 = 1.f / (od[0] + 1e-8f);
    float r1 = 1.f / (od[1] + 1e-8f);
    float r2 = 1.f / (od[2] + 1e-8f);
    float sR = __fadd_rn(__fadd_rn(r0, r1), r2);
    long obase = ((long)b * NN + q) * 3;
    wW[obase + 0] = r0 / sR; wW[obase + 1] = r1 / sR; wW[obase + 2] = r2 / sR;
    wIdx[obase + 0] = oi[0]; wIdx[obase + 1] = oi[1]; wIdx[obase + 2] = oi[2];
  }
}

// ---------- fill interp channels of nt (cols 128..383) ----------
__global__ __launch_bounds__(256) void interp_fill_k(const float* __restrict__ p2t,
                                                     const float* __restrict__ wW,
                                                     const int* __restrict__ wIdx,
                                                     float* __restrict__ nt) {
  const int q = (blockIdx.x << 1) + (threadIdx.x >> 7);
  const int co = threadIdx.x & 127;
  const int b = q >> 12;
  long wb = (long)q * 3;
  float w0 = wW[wb], w1 = wW[wb + 1], w2 = wW[wb + 2];
  int i0 = wIdx[wb], i1 = wIdx[wb + 1], i2 = wIdx[wb + 2];
  const float* r0 = p2t + ((long)(b << 10) + i0) * NC2;
  const float* r1 = p2t + ((long)(b << 10) + i1) * NC2;
  const float* r2 = p2t + ((long)(b << 10) + i2) * NC2;
  float* orow = nt + (long)q * NCC + NC1;
#pragma unroll
  for (int h = 0; h < 2; ++h) {
    int c = co + 128 * h;
    orow[c] = w0 * r0[c] + w1 * r1[c] + w2 * r2[c];
  }
}

// ---------- f32 tiled GEMM: 64 rows x 64 output channels per block ----------
// grid (M/64, CO/64) = (256, 2) -> 512 blocks = 2 blocks/CU = 2 waves/SIMD.
template <int C>
__global__ __launch_bounds__(256) void gemm_bias_k(const float* __restrict__ feat,
                                                   const float* __restrict__ W,
                                                   const float* __restrict__ bias,
                                                   float* __restrict__ out) {
  __shared__ float fL[64][36];
  __shared__ float wL[64][36];
  const int r0 = blockIdx.x * 64;
  const int ob = blockIdx.y * 64;
  const int tid = threadIdx.x;
  const int tn = tid & 15;
  const int to = tid >> 4;
  float acc[4][4];
#pragma unroll
  for (int i = 0; i < 4; ++i)
#pragma unroll
    for (int j = 0; j < 4; ++j) acc[i][j] = 0.f;

  for (int c0 = 0; c0 < C; c0 += 32) {
#pragma unroll
    for (int k = 0; k < 8; ++k) {
      int e = tid + 256 * k;
      int rr = e >> 5, cc = e & 31;
      fL[rr][cc] = feat[(long)(r0 + rr) * C + c0 + cc];
    }
#pragma unroll
    for (int k = 0; k < 8; ++k) {
      int e = tid + 256 * k;
      int rr = e >> 5, cc = e & 31;
      wL[rr][cc] = W[(long)(ob + rr) * C + c0 + cc];
    }
    __syncthreads();
#pragma unroll
    for (int cc4 = 0; cc4 < 32; cc4 += 4) {
      float4 fv[4], wv[4];
#pragma unroll
      for (int i = 0; i < 4; ++i) fv[i] = *(const float4*)&fL[tn + 16 * i][cc4];
#pragma unroll
      for (int j = 0; j < 4; ++j) wv[j] = *(const float4*)&wL[to + 16 * j][cc4];
#pragma unroll
      for (int i = 0; i < 4; ++i)
#pragma unroll
        for (int j = 0; j < 4; ++j) {
          acc[i][j] += fv[i].x * wv[j].x + fv[i].y * wv[j].y +
                       fv[i].z * wv[j].z + fv[i].w * wv[j].w;
        }
    }
    __syncthreads();
  }
  const int b = r0 >> 12;
  const int n0 = r0 & 4095;
#pragma unroll
  for (int i = 0; i < 4; ++i) {
    int n = n0 + tn + 16 * i;
#pragma unroll
    for (int j = 0; j < 4; ++j) {
      int o = ob + to + 16 * j;
      out[((long)(b * NCO + o) << 12) + n] = acc[i][j] + bias[o];
    }
  }
}

// ---------- BN stats per channel over (B, N): single pass (sum, sumsq) ----------
__global__ __launch_bounds__(256) void bn_stats_k(const float* __restrict__ v,
                                                  const float* __restrict__ gamma,
                                                  const float* __restrict__ beta,
                                                  float* __restrict__ stats, int relu_in) {
  __shared__ float rs[256], rq[256];
  const int o = blockIdx.x, tid = threadIdx.x;
  float s = 0.f, ss = 0.f;
  for (int i = tid; i < NB * NN; i += 256) {
    int b = i >> 12, n = i & 4095;
    float val = v[(((long)b * NCO + o) << 12) + n];
    if (relu_in) val = fmaxf(val, 0.f);
    s += val;
    ss += val * val;
  }
  rs[tid] = s; rq[tid] = ss;
  __syncthreads();
  for (int off = 128; off > 0; off >>= 1) {
    if (tid < off) { rs[tid] += rs[tid + off]; rq[tid] += rq[tid + off]; }
    __syncthreads();
  }
  if (tid == 0) {
    float m = rs[0] * (1.f / 16384.f);
    float var = rq[0] * (1.f / 16384.f) - m * m;
    var = fmaxf(var, 0.f);
    float inv = rsqrtf(var + 1e-5f);
    stats[o] = m;
    stats[128 + o] = inv * gamma[o];
    stats[256 + o] = beta[o];
  }
}

// ---------- apply fuse BN + ReLU (tiled): write x [B,CO,N] + xt [B,N,CO] ----------
// 32x32 LDS tile makes BOTH writes coalesced (old version wrote xt at stride
// 512B = 1 dword/cacheline, ~16x write amplification).
// grid (N/32, CO/32, B), block (32,8).
__global__ void fuse_apply_k(const float* __restrict__ xp, const float* __restrict__ stats,
                             float* __restrict__ x, float* __restrict__ xt) {
  __shared__ float tile[32][33];
  const int b = blockIdx.z;
  const int n0 = blockIdx.x * 32;
  const int o0 = blockIdx.y * 32;
  const int tx = threadIdx.x, ty = threadIdx.y;
#pragma unroll
  for (int k = 0; k < 32; k += 8) {
    int o = o0 + ty + k;
    long idx = (((long)b * NCO + o) << 12) + n0 + tx;
    float v = (xp[idx] - stats[o]) * stats[128 + o] + stats[256 + o];
    v = fmaxf(v, 0.f);
    x[idx] = v;
    tile[ty + k][tx] = v;
  }
  __syncthreads();
#pragma unroll
  for (int k = 0; k < 32; k += 8) {
    int n = n0 + ty + k;
    xt[((long)(b << 12) + n) * NCO + o0 + tx] = tile[tx][ty + k];
  }
}

// ---------- KNN(16): tau + BALLOT compaction; 32 q x 8 lanes; 4-way ILP ----------
// Pass 1: FOUR independent top-2 trackers per lane (strides i, i+8, i+16,
//   i+24) -> union combine (equality-select; ties make tau looser, which is
//   SAFE: per-lane tau >= 2nd-smallest of the lane's stream, so >=16
//   candidates of the query have d <= tau after the lane-max reduce).
// Pass 2: 4 distances + 4 ballots per iteration; deterministic positions via
//   popc prefix sums; register count, no atomics. Order changes within an
//   iteration but pass 3 is order-independent -> output bit-identical.
// Pass 3: order-independent lex-(d,idx) ladder + 8-way lex merge (proven).
// Overflow (mycnt > KCAP=160, P ~3.5e-7/query): tau-guarded global rescan.
__global__ __launch_bounds__(256) void knn_k(const float* __restrict__ xyz1,
                                             int* __restrict__ knn) {
  __shared__ float4 sc[KCHUNK];      // 32 KB; reused as merge lists at the end
  __shared__ float bufd[32][KPAD];   // 20.1 KB
  __shared__ int bufi[32][KPAD];     // 20.1 KB
  const int b = blockIdx.y;
  const int tid = threadIdx.x;
  const int ql = tid >> 3;
  const int q = (blockIdx.x << 5) + ql;
  const int lane = tid & 7;
  const int gb = (tid & 63) - lane;  // group base lane within the wave
  const long qb = ((long)b * NN + q) * 3;
  const float qx = xyz1[qb], qy = xyz1[qb + 1], qz = xyz1[qb + 2];
  const float nq = norm3_np(qx, qy, qz);

  // ---- pass 1: tau via FOUR independent top-2 trackers ----
  float ta0 = FLT_MAX, ta1 = FLT_MAX, tb0 = FLT_MAX, tb1 = FLT_MAX;
  float tc0 = FLT_MAX, tc1 = FLT_MAX, td0 = FLT_MAX, td1 = FLT_MAX;
  for (int ch = 0; ch < 2; ++ch) {
    for (int i = tid; i < KCHUNK; i += 256) {
      long base = ((long)b * NN + ch * KCHUNK + i) * 3;
      float x = xyz1[base], y = xyz1[base + 1], z = xyz1[base + 2];
      sc[i] = make_float4(x, y, z, norm3_np(x, y, z));
    }
    __syncthreads();
    for (int i = lane; i < KCHUNK; i += 32) {
      float4 v0 = sc[i], v1 = sc[i + 8], v2 = sc[i + 16], v3 = sc[i + 24];
      float d0 = sqdist_np(nq, v0.w, qx, qy, qz, v0.x, v0.y, v0.z);
      float d1 = sqdist_np(nq, v1.w, qx, qy, qz, v1.x, v1.y, v1.z);
      float d2 = sqdist_np(nq, v2.w, qx, qy, qz, v2.x, v2.y, v2.z);
      float d3 = sqdist_np(nq, v3.w, qx, qy, qz, v3.x, v3.y, v3.z);
      float h0 = fmaxf(d0, ta0); ta0 = fminf(d0, ta0); ta1 = fminf(h0, ta1);
      float h1 = fmaxf(d1, tb0); tb0 = fminf(d1, tb0); tb1 = fminf(h1, tb1);
      float h2 = fmaxf(d2, tc0); tc0 = fminf(d2, tc0); tc1 = fminf(h2, tc1);
      float h3 = fmaxf(d3, td0); td0 = fminf(d3, td0); td1 = fminf(h3, td1);
    }
    __syncthreads();
  }
  // union combine: lane 2nd-smallest (exact ties -> looser tau: still safe)
  float m1 = fminf(fminf(ta0, tb0), fminf(tc0, td0));
  float s0 = (ta0 == m1) ? ta1 : ta0;
  float s1 = (tb0 == m1) ? tb1 : tb0;
  float s2 = (tc0 == m1) ? tc1 : tc0;
  float s3 = (td0 == m1) ? td1 : td0;
  float tau = fminf(fminf(s0, s1), fminf(s2, s3));
  tau = fmaxf(tau, __shfl_xor(tau, 1, 64));
  tau = fmaxf(tau, __shfl_xor(tau, 2, 64));
  tau = fmaxf(tau, __shfl_xor(tau, 4, 64));

  // ---- pass 2: ballot-compacted survivor collection (4-way ILP) ----
  int mycnt = 0;  // survivor count for this query; uniform across its 8 lanes
  for (int ch = 0; ch < 2; ++ch) {
    for (int i = tid; i < KCHUNK; i += 256) {
      long base = ((long)b * NN + ch * KCHUNK + i) * 3;
      float x = xyz1[base], y = xyz1[base + 1], z = xyz1[base + 2];
      sc[i] = make_float4(x, y, z, norm3_np(x, y, z));
    }
    __syncthreads();
    const int cb = ch * KCHUNK;
    for (int i = lane; i < KCHUNK; i += 32) {
      float4 v0 = sc[i], v1 = sc[i + 8], v2 = sc[i + 16], v3 = sc[i + 24];
      float d0 = sqdist_np(nq, v0.w, qx, qy, qz, v0.x, v0.y, v0.z);
      float d1 = sqdist_np(nq, v1.w, qx, qy, qz, v1.x, v1.y, v1.z);
      float d2 = sqdist_np(nq, v2.w, qx, qy, qz, v2.x, v2.y, v2.z);
      float d3 = sqdist_np(nq, v3.w, qx, qy, qz, v3.x, v3.y, v3.z);
      bool sv0 = (d0 <= tau), sv1 = (d1 <= tau), sv2 = (d2 <= tau), sv3 = (d3 <= tau);
      unsigned long long m0 = __ballot(sv0);
      unsigned long long m1b = __ballot(sv1);
      unsigned long long m2 = __ballot(sv2);
      unsigned long long m3 = __ballot(sv3);
      unsigned g0 = (unsigned)((m0 >> gb) & 0xFFull);
      unsigned g1 = (unsigned)((m1b >> gb) & 0xFFull);
      unsigned g2 = (unsigned)((m2 >> gb) & 0xFFull);
      unsigned g3 = (unsigned)((m3 >> gb) & 0xFFull);
      unsigned below = (1u << lane) - 1u;
      int c0p = __popc(g0), c1p = __popc(g1), c2p = __popc(g2);
      if (sv0) {
        int pos = mycnt + __popc(g0 & below);
        if (pos < KCAP) { bufd[ql][pos] = d0; bufi[ql][pos] = cb + i; }
      }
      if (sv1) {
        int pos = mycnt + c0p + __popc(g1 & below);
        if (pos < KCAP) { bufd[ql][pos] = d1; bufi[ql][pos] = cb + i + 8; }
      }
      if (sv2) {
        int pos = mycnt + c0p + c1p + __popc(g2 & below);
        if (pos < KCAP) { bufd[ql][pos] = d2; bufi[ql][pos] = cb + i + 16; }
      }
      if (sv3) {
        int pos = mycnt + c0p + c1p + c2p + __popc(g3 & below);
        if (pos < KCAP) { bufd[ql][pos] = d3; bufi[ql][pos] = cb + i + 24; }
      }
      mycnt += c0p + c1p + c2p + __popc(g3);
    }
    __syncthreads();
  }

  // ---- pass 3: exact stable top-16 ----
  float bd[NK]; int bi[NK];
#pragma unroll
  for (int j = 0; j < NK; ++j) { bd[j] = FLT_MAX; bi[j] = 0x7fffffff; }
  if (mycnt > KCAP) {
    // fallback: tau-guarded strict-d ladder over global (index order -> stable)
    for (int s = lane; s < NN; s += 8) {
      long base = ((long)b * NN + s) * 3;
      float x = xyz1[base], y = xyz1[base + 1], z = xyz1[base + 2];
      float d = sqdist_np(nq, norm3_np(x, y, z), qx, qy, qz, x, y, z);
      if (d <= tau) {
        float cd = d; int ci = s;
#pragma unroll
        for (int j = 0; j < NK; ++j) {
          bool lt = cd < bd[j];
          float dmin = fminf(cd, bd[j]);
          float dmax = fmaxf(cd, bd[j]);
          int imin = lt ? ci : bi[j];
          int imax = lt ? bi[j] : ci;
          bd[j] = dmin; bi[j] = imin; cd = dmax; ci = imax;
        }
      }
    }
  } else {
    for (int j0 = lane; j0 < mycnt; j0 += 8) {
      float cd = bufd[ql][j0]; int ci = bufi[ql][j0];
#pragma unroll
      for (int j = 0; j < NK; ++j) {
        bool lt = (cd < bd[j]) || (cd == bd[j] && ci < bi[j]);  // lex (d, idx)
        float nd = lt ? cd : bd[j];
        float xd = lt ? bd[j] : cd;
        int ni = lt ? ci : bi[j];
        int xi = lt ? bi[j] : ci;
        bd[j] = nd; bi[j] = ni; cd = xd; ci = xi;
      }
    }
  }
  __syncthreads();  // staging LDS dead; reuse sc for merge lists

  float* md = (float*)sc;        // 256*16 floats = 16 KB
  int* mi = (int*)sc + 4096;     // 256*16 ints  = 16 KB
#pragma unroll
  for (int j = 0; j < NK; ++j) { md[tid * NK + j] = bd[j]; mi[tid * NK + j] = bi[j]; }
  __syncthreads();
  if (lane == 0) {
    int p0 = 0, p1 = 0, p2 = 0, p3 = 0, p4 = 0, p5 = 0, p6 = 0, p7 = 0;
    long obase = ((long)b * NN + q) * NK;
    for (int j = 0; j < NK; ++j) {
      float bv = FLT_MAX; int bidx = 0x7fffffff; int bl = 0;
#define KNN_CAND(l, pl)                                                      \
      {                                                                      \
        float t = (pl < NK) ? md[(tid + l) * NK + pl] : FLT_MAX;             \
        int ti = (pl < NK) ? mi[(tid + l) * NK + pl] : 0x7fffffff;           \
        if (t < bv || (t == bv && ti < bidx)) { bv = t; bidx = ti; bl = l; } \
      }
      KNN_CAND(0, p0) KNN_CAND(1, p1) KNN_CAND(2, p2) KNN_CAND(3, p3)
      KNN_CAND(4, p4) KNN_CAND(5, p5) KNN_CAND(6, p6) KNN_CAND(7, p7)
#undef KNN_CAND
      knn[obase + j] = bidx;
      p0 += (bl == 0); p1 += (bl == 1); p2 += (bl == 2); p3 += (bl == 3);
      p4 += (bl == 4); p5 += (bl == 5); p6 += (bl == 6); p7 += (bl == 7);
    }
  }
}

// ---------- Laplacian gather: dxt[q][o] = sum_k xt[nbr_k][o] - xt[q][o] ----------
__global__ __launch_bounds__(256) void lap_gather_k(const float* __restrict__ xt,
                                                    const int* __restrict__ knn,
                                                    float* __restrict__ dxt) {
  const int q = (blockIdx.x << 1) + (threadIdx.x >> 7);
  const int o = threadIdx.x & 127;
  const int b = q >> 12;
  const int* kid = knn + (long)q * NK;
  const long bb = ((long)b << 12) * NCO;
  float s = 0.f;
#pragma unroll
  for (int k = 0; k < NK; ++k) {
    int m = kid[k];
    s += xt[bb + (long)m * NCO + o];
  }
  dxt[(long)q * NCO + o] = s - xt[(long)q * NCO + o];
}

// ---------- final: out = x + BN(relu(h_pre)) ----------
__global__ void final_k(const float* __restrict__ x, const float* __restrict__ hp,
                        const float* __restrict__ stats, float* __restrict__ out) {
  const int stride = gridDim.x * blockDim.x;
  for (int idx = blockIdx.x * blockDim.x + threadIdx.x; idx < NB * NCO * NN; idx += stride) {
    int o = (idx >> 12) & 127;
    float r = fmaxf(hp[idx], 0.f);
    out[idx] = x[idx] + (r - stats[o]) * stats[128 + o] + stats[256 + o];
  }
}

extern "C" void kernel_launch(void* const* d_in, const int* in_sizes, int n_in,
                              void* d_out, int out_size, void* d_ws, size_t ws_size,
                              hipStream_t stream) {
  const float* xyz1 = (const float*)d_in[0];
  const float* xyz2 = (const float*)d_in[1];
  const float* points1 = (const float*)d_in[2];
  const float* points2 = (const float*)d_in[3];
  const float* fuse_w = (const float*)d_in[4];
  const float* fuse_b = (const float*)d_in[5];
  const float* fuse_g = (const float*)d_in[6];
  const float* fuse_be = (const float*)d_in[7];
  const float* lu_w = (const float*)d_in[8];
  const float* lu_b = (const float*)d_in[9];
  const float* lu_g = (const float*)d_in[10];
  const float* lu_be = (const float*)d_in[11];
  (void)in_sizes; (void)n_in; (void)out_size; (void)ws_size;

  char* ws = (char*)d_ws;
  float* p2t = (float*)(ws);                   // 4,194,304 B  [B,S,C2]
  float* wW = (float*)(ws + 4194304);          //   196,608 B  [B,N,3]
  int* wIdx = (int*)(ws + 4390912);            //   196,608 B
  float* st1 = (float*)(ws + 4587520);         //     1,536 B
  float* st2 = (float*)(ws + 4589056);         //     1,536 B
  int* knn = (int*)(ws + 4590592);             // 1,048,576 B  [B,N,16]
  float* nt = (float*)(ws + 5639168);          // 25,165,824 B [B*N,384]
  float* xp = (float*)(ws + 30804992);         // 8,388,608 B  [B,CO,N]
  float* x = (float*)(ws + 39193600);          // 8,388,608 B  [B,CO,N]
  // nt is dead after the fuse GEMM -> reuse its 25.1 MB for xt/dxt/hp
  float* xt = nt;                  // [B,N,CO]
  float* dxt = nt + 2097152;       // [B*N,CO]
  float* hp = nt + 4194304;        // [B,CO,N]

  dim3 tb(32, 8);
  transpose_k<<<dim3(32, 8, NB), tb, 0, stream>>>(points2, p2t, 256, 1024, 262144L, 262144L, 256);
  transpose_k<<<dim3(128, 4, NB), tb, 0, stream>>>(points1, nt, 128, 4096, 524288L, 1572864L, 384);
  interp_top3_k<<<dim3(128, NB), 256, 0, stream>>>(xyz1, xyz2, wW, wIdx);
  interp_fill_k<<<8192, 256, 0, stream>>>(p2t, wW, wIdx, nt);
  gemm_bias_k<NCC><<<dim3(256, 2), 256, 0, stream>>>(nt, fuse_w, fuse_b, xp);
  bn_stats_k<<<128, 256, 0, stream>>>(xp, fuse_g, fuse_be, st1, 0);
  fuse_apply_k<<<dim3(128, 4, NB), tb, 0, stream>>>(xp, st1, x, xt);
  knn_k<<<dim3(128, NB), 256, 0, stream>>>(xyz1, knn);
  lap_gather_k<<<8192, 256, 0, stream>>>(xt, knn, dxt);
  gemm_bias_k<NCO><<<dim3(256, 2), 256, 0, stream>>>(dxt, lu_w, lu_b, hp);
  bn_stats_k<<<128, 256, 0, stream>>>(hp, lu_g, lu_be, st2, 1);
  final_k<<<2048, 256, 0, stream>>>(x, hp, st2, (float*)d_out);
}